// Round 1
// baseline (55.223 us; speedup 1.0000x reference)
//
#include <hip/hip_runtime.h>
#include <cstdint>
#include <cstddef>

constexpr int CDIM   = 256;   // channels
constexpr int CR     = 64;    // reduced channels
constexpr int NROW   = 4096;  // tokens per batch
constexpr int NBATCH = 8;
constexpr int ROWS_PER_BLOCK   = 64;
constexpr int BLOCKS_PER_BATCH = NROW / ROWS_PER_BLOCK; // 64

// ---------------------------------------------------------------- init ----
__global__ __launch_bounds__(256) void k_init(float* __restrict__ S,
                                              unsigned long long* __restrict__ amax) {
    int t = blockIdx.x * 256 + threadIdx.x;
    if (t < NBATCH * CDIM) S[t] = 0.0f;
    if (t < NBATCH)        amax[t] = 0ULL;
}

// ------------------------------------------------- pass 1: S = sum of u ----
// One block = 64 rows of one batch. 4 waves x 16 rows. Each wave handles a
// full row (64 lanes x float4 = 256 floats) with shuffle reductions.
__global__ __launch_bounds__(256) void k_accum(const float* __restrict__ x,
                                               float* __restrict__ S) {
    const int blk   = blockIdx.x;
    const int b     = blk / BLOCKS_PER_BATCH;
    const int chunk = blk % BLOCKS_PER_BATCH;
    const int wave  = threadIdx.x >> 6;
    const int lane  = threadIdx.x & 63;
    const float* xb = x + (size_t)b * NROW * CDIM;

    float acc0 = 0.f, acc1 = 0.f, acc2 = 0.f, acc3 = 0.f;
    const int nbase = chunk * ROWS_PER_BLOCK + wave * 16;

    for (int r = 0; r < 16; ++r) {
        const float4 v = *reinterpret_cast<const float4*>(
            xb + (size_t)(nbase + r) * CDIM + lane * 4);
        float sa = v.x + v.y + v.z + v.w;
        float sb = v.x * v.x + v.y * v.y + v.z * v.z + v.w * v.w;
#pragma unroll
        for (int off = 1; off < 64; off <<= 1) {
            sa += __shfl_xor(sa, off, 64);
            sb += __shfl_xor(sb, off, 64);
        }
        const float mu  = sa * (1.0f / CDIM);
        const float ss  = sb - sa * mu;       // sum (v-mu)^2
        const float inv = rsqrtf(ss);         // u = (v-mu)/||v-mu||  (eps cancels)
        acc0 += (v.x - mu) * inv;
        acc1 += (v.y - mu) * inv;
        acc2 += (v.z - mu) * inv;
        acc3 += (v.w - mu) * inv;
    }

    __shared__ float lds[4][CDIM];
    *reinterpret_cast<float4*>(&lds[wave][lane * 4]) =
        make_float4(acc0, acc1, acc2, acc3);
    __syncthreads();

    const int c = threadIdx.x;
    const float s = lds[0][c] + lds[1][c] + lds[2][c] + lds[3][c];
    atomicAdd(&S[b * CDIM + c], s);
}

// --------------------------------- pass 2: density = u . S, batch argmax ----
__global__ __launch_bounds__(256) void k_argmax(const float* __restrict__ x,
                                                const float* __restrict__ S,
                                                unsigned long long* __restrict__ amax) {
    const int blk   = blockIdx.x;
    const int b     = blk / BLOCKS_PER_BATCH;
    const int chunk = blk % BLOCKS_PER_BATCH;
    const int wave  = threadIdx.x >> 6;
    const int lane  = threadIdx.x & 63;
    const float* xb = x + (size_t)b * NROW * CDIM;

    const float4 Sv = *reinterpret_cast<const float4*>(S + b * CDIM + lane * 4);
    float sumS = Sv.x + Sv.y + Sv.z + Sv.w;
#pragma unroll
    for (int off = 1; off < 64; off <<= 1) sumS += __shfl_xor(sumS, off, 64);

    float best  = -1e30f;
    int   bestn = 0;
    const int nbase = chunk * ROWS_PER_BLOCK + wave * 16;

    for (int r = 0; r < 16; ++r) {
        const int n = nbase + r;
        const float4 v = *reinterpret_cast<const float4*>(
            xb + (size_t)n * CDIM + lane * 4);
        float sa = v.x + v.y + v.z + v.w;
        float sb = v.x * v.x + v.y * v.y + v.z * v.z + v.w * v.w;
        float sc = v.x * Sv.x + v.y * Sv.y + v.z * Sv.z + v.w * Sv.w;
#pragma unroll
        for (int off = 1; off < 64; off <<= 1) {
            sa += __shfl_xor(sa, off, 64);
            sb += __shfl_xor(sb, off, 64);
            sc += __shfl_xor(sc, off, 64);
        }
        const float mu   = sa * (1.0f / CDIM);
        const float ss   = sb - sa * mu;       // sum (v-mu)^2
        const float dotS = sc - mu * sumS;     // (v-mu) . S
        const float dens = dotS * rsqrtf(ss);
        if (dens > best) { best = dens; bestn = n; }
    }

    if (lane == 0) {
        unsigned key = __float_as_uint(best);
        key = (key & 0x80000000u) ? ~key : (key | 0x80000000u);  // order-preserving
        const unsigned long long packed =
            ((unsigned long long)key << 32) | (unsigned)bestn;
        atomicMax(amax + b, packed);
    }
}

// -------------------------------- pass 3: LN(argmax row) -> proj -> relu ----
__global__ __launch_bounds__(256) void k_out(const float* __restrict__ x,
                                             const float* __restrict__ lnw,
                                             const float* __restrict__ lnb,
                                             const float* __restrict__ pw,
                                             const float* __restrict__ pb,
                                             const unsigned long long* __restrict__ amax,
                                             float* __restrict__ out) {
    const int b    = blockIdx.x;
    const int t    = threadIdx.x;
    const int wave = t >> 6;
    const int lane = t & 63;
    const int n    = (int)(amax[b] & 0xFFFFFFFFULL);

    const float* row = x + ((size_t)b * NROW + n) * CDIM;
    const float v = row[t];

    __shared__ float red[8];
    __shared__ float y[CDIM];

    float s = v;
#pragma unroll
    for (int off = 1; off < 64; off <<= 1) s += __shfl_xor(s, off, 64);
    if (lane == 0) red[wave] = s;
    __syncthreads();
    const float mu = (red[0] + red[1] + red[2] + red[3]) * (1.0f / CDIM);

    const float d = v - mu;
    float s2 = d * d;
#pragma unroll
    for (int off = 1; off < 64; off <<= 1) s2 += __shfl_xor(s2, off, 64);
    if (lane == 0) red[4 + wave] = s2;
    __syncthreads();
    const float var = (red[4] + red[5] + red[6] + red[7]) * (1.0f / CDIM);
    const float rs  = rsqrtf(var + 1e-5f);

    y[t] = d * rs * lnw[t] + lnb[t];
    __syncthreads();

    // 64 outputs, 4 partials each: thread t -> (dcol = t>>2, part = t&3)
    const int dcol = t >> 2;
    const int part = t & 3;
    const float* wrow = pw + dcol * CDIM + part * 64;
    const float* yp   = y + part * 64;
    float p = 0.f;
#pragma unroll
    for (int c = 0; c < 64; ++c) p += yp[c] * wrow[c];
    p += __shfl_xor(p, 1, 64);
    p += __shfl_xor(p, 2, 64);
    if (part == 0) out[b * CR + dcol] = fmaxf(p + pb[dcol], 0.0f);
}

// --------------------------------------------------------------- launch ----
extern "C" void kernel_launch(void* const* d_in, const int* in_sizes, int n_in,
                              void* d_out, int out_size, void* d_ws, size_t ws_size,
                              hipStream_t stream) {
    const float* x   = (const float*)d_in[0];
    const float* lnw = (const float*)d_in[1];
    const float* lnb = (const float*)d_in[2];
    const float* pw  = (const float*)d_in[3];
    const float* pb  = (const float*)d_in[4];
    float* out = (float*)d_out;

    float* S = (float*)d_ws;                                         // 8*256 f32
    unsigned long long* amax =
        (unsigned long long*)((char*)d_ws + NBATCH * CDIM * sizeof(float)); // 8*u64

    k_init<<<8, 256, 0, stream>>>(S, amax);
    k_accum<<<NBATCH * BLOCKS_PER_BATCH, 256, 0, stream>>>(x, S);
    k_argmax<<<NBATCH * BLOCKS_PER_BATCH, 256, 0, stream>>>(x, S, amax);
    k_out<<<NBATCH, 256, 0, stream>>>(x, lnw, lnb, pw, pb, amax, out);
}